// Round 1
// baseline (64.259 us; speedup 1.0000x reference)
//
#include <hip/hip_runtime.h>
#include <math.h>

#define TWO_PI_F 6.2831853071795864769f
#define EPS_F 1e-6f
#define PI_F 3.14159265358979323846f

// Compute the Kent orthonormal frame (g1,g2,g3) from angles.
__device__ __forceinline__ void kent_frame(float eta, float alpha, float psi,
                                           float& g1x, float& g1y, float& g1z,
                                           float& g2x, float& g2y, float& g2z,
                                           float& g3x, float& g3y, float& g3z) {
    float ca = cosf(alpha), sa = sinf(alpha);
    float ce = cosf(eta),   se = sinf(eta);
    float cp = cosf(psi),   sp = sinf(psi);
    g1x = ca;        g1y = sa * ce;                  g1z = sa * se;
    g2x = -cp * sa;  g2y = cp * ca * ce - sp * se;   g2z = cp * ca * se + sp * ce;
    g3x = sp * sa;   g3y = -sp * ca * ce - cp * se;  g3z = -sp * ca * se + cp * ce;
}

// One thread per row (pred rows then target rows).
// fw: [N][10]  = {Ex0,Ex1,Ex2, S00,S11,S22, 2S01,2S02,2S12, A}
// gw: [10][M]  = {kb*gb1(3), bb*Ddiag(3), bb*Doff(3), c_b}  (transposed for coalescing)
__global__ __launch_bounds__(256) void kent_precompute(
    const float* __restrict__ pred, const float* __restrict__ targ,
    float* __restrict__ fw, float* __restrict__ gw, int N, int M)
{
    int i = blockIdx.x * blockDim.x + threadIdx.x;
    if (i < N) {
        const float* r = pred + (size_t)i * 5;
        float eta = r[0], alpha = r[1], psi = r[2], kap = r[3], bet = r[4];
        float g1x,g1y,g1z,g2x,g2y,g2z,g3x,g3y,g3z;
        kent_frame(eta, alpha, psi, g1x,g1y,g1z, g2x,g2y,g2z, g3x,g3y,g3z);

        float km = kap - 2.f*bet, kp = kap + 2.f*bet;
        float lkm = logf(km), lkp = logf(kp);
        float c   = logf(TWO_PI_F) + kap - 0.5f*logf(km*kp + EPS_F);
        // log_del_kappa: log(-2pi(4b^2 + k - k^2)) = log(2pi(k^2 - k - 4b^2))
        float b2 = bet*bet;
        float ck  = logf(TWO_PI_F*(kap*kap - kap - 4.f*b2)) + kap
                  - (1.5f*lkm + 1.5f*lkp + EPS_F);
        float k2 = kap*kap;
        float poly = k2*k2 - 2.f*kap*k2 + (2.f - 8.f*b2)*k2 + 8.f*b2*kap
                   + 16.f*b2*b2 + 4.f*b2;
        float ckk = logf(TWO_PI_F*poly) + kap - (2.5f*lkm + 2.5f*lkp + EPS_F);
        float cbt = logf(8.f*PI_F*kap) + logf(bet) - (1.5f*lkm + 1.5f*lkp + EPS_F);

        float l1  = expf(ck  - c);
        float ekk = expf(ckk - c);
        float eb  = expf(cbt - c);
        float l2 = 0.5f*(1.f - ekk + eb);
        float l3 = 0.5f*(1.f - ekk - eb);

        float Ex = l1*g1x, Ey = l1*g1y, Ez = l1*g1z;
        float S00 = l1*g1x*g1x + l2*g2x*g2x + l3*g3x*g3x;
        float S11 = l1*g1y*g1y + l2*g2y*g2y + l3*g3y*g3y;
        float S22 = l1*g1z*g1z + l2*g2z*g2z + l3*g3z*g3z;
        float S01 = l1*g1x*g1y + l2*g2x*g2y + l3*g3x*g3y;
        float S02 = l1*g1x*g1z + l2*g2x*g2z + l3*g3x*g3z;
        float S12 = l1*g1y*g1z + l2*g2y*g2z + l3*g3y*g3z;

        // qa2 = g2^T S g2 ; qa3 = g3^T S g3 (numerically, matching reference)
        float qa2 = S00*g2x*g2x + S11*g2y*g2y + S22*g2z*g2z
                  + 2.f*(S01*g2x*g2y + S02*g2x*g2z + S12*g2y*g2z);
        float qa3 = S00*g3x*g3x + S11*g3y*g3y + S22*g3z*g3z
                  + 2.f*(S01*g3x*g3y + S02*g3x*g3z + S12*g3y*g3z);
        float dg1Ex = g1x*Ex + g1y*Ey + g1z*Ez;
        float A = -c + kap*dg1Ex + bet*(qa2 - qa3);

        float* f = fw + (size_t)i * 10;
        f[0]=Ex; f[1]=Ey; f[2]=Ez;
        f[3]=S00; f[4]=S11; f[5]=S22;
        f[6]=2.f*S01; f[7]=2.f*S02; f[8]=2.f*S12;
        f[9]=A;
    } else if (i < N + M) {
        int m = i - N;
        const float* r = targ + (size_t)m * 5;
        float eta = r[0], alpha = r[1], psi = r[2], kap = r[3], bet = r[4];
        float g1x,g1y,g1z,g2x,g2y,g2z,g3x,g3y,g3z;
        kent_frame(eta, alpha, psi, g1x,g1y,g1z, g2x,g2y,g2z, g3x,g3y,g3z);

        float km = kap - 2.f*bet, kp = kap + 2.f*bet;
        float cB = logf(TWO_PI_F) + kap - 0.5f*logf(km*kp + EPS_F);

        float D00 = g2x*g2x - g3x*g3x;
        float D11 = g2y*g2y - g3y*g3y;
        float D22 = g2z*g2z - g3z*g3z;
        float D01 = g2x*g2y - g3x*g3y;
        float D02 = g2x*g2z - g3x*g3z;
        float D12 = g2y*g2z - g3y*g3z;

        gw[0*(size_t)M + m] = kap*g1x;
        gw[1*(size_t)M + m] = kap*g1y;
        gw[2*(size_t)M + m] = kap*g1z;
        gw[3*(size_t)M + m] = bet*D00;
        gw[4*(size_t)M + m] = bet*D11;
        gw[5*(size_t)M + m] = bet*D22;
        gw[6*(size_t)M + m] = bet*D01;
        gw[7*(size_t)M + m] = bet*D02;
        gw[8*(size_t)M + m] = bet*D12;
        gw[9*(size_t)M + m] = cB;
    }
}

// out[n,m] = A[n] + B[m] - sum_k f[n,k]*g[m,k]
// Each block: 8 n-rows x 1024 m-cols. Each thread: 4 m via float4, 8 n.
__global__ __launch_bounds__(256) void kent_kld_main(
    const float* __restrict__ fw, const float* __restrict__ gw,
    float* __restrict__ out, int N, int M)
{
    int t = threadIdx.x;
    int m0 = blockIdx.x * 1024 + t * 4;
    int n0 = blockIdx.y * 8;
    if (m0 >= M) return;

    if (m0 + 3 < M) {
        float4 G[10];
#pragma unroll
        for (int k = 0; k < 10; ++k)
            G[k] = *(const float4*)(&gw[(size_t)k * M + m0]);
#pragma unroll
        for (int rr = 0; rr < 8; ++rr) {
            int n = n0 + rr;
            if (n >= N) break;
            const float* f = fw + (size_t)n * 10;
            float A = f[9];
            float4 o;
            o.x = A + G[9].x; o.y = A + G[9].y;
            o.z = A + G[9].z; o.w = A + G[9].w;
#pragma unroll
            for (int k = 0; k < 9; ++k) {
                float fk = f[k];
                o.x = fmaf(-fk, G[k].x, o.x);
                o.y = fmaf(-fk, G[k].y, o.y);
                o.z = fmaf(-fk, G[k].z, o.z);
                o.w = fmaf(-fk, G[k].w, o.w);
            }
            *(float4*)(&out[(size_t)n * M + m0]) = o;
        }
    } else {
        // scalar tail (unused for M=2048 but keeps generality)
        for (int mm = m0; mm < M; ++mm) {
            for (int rr = 0; rr < 8; ++rr) {
                int n = n0 + rr;
                if (n >= N) break;
                const float* f = fw + (size_t)n * 10;
                float acc = f[9] + gw[9*(size_t)M + mm];
                for (int k = 0; k < 9; ++k)
                    acc = fmaf(-f[k], gw[(size_t)k * M + mm], acc);
                out[(size_t)n * M + mm] = acc;
            }
        }
    }
}

extern "C" void kernel_launch(void* const* d_in, const int* in_sizes, int n_in,
                              void* d_out, int out_size, void* d_ws, size_t ws_size,
                              hipStream_t stream) {
    const float* pred = (const float*)d_in[0];
    const float* targ = (const float*)d_in[1];
    int N = in_sizes[0] / 5;
    int M = in_sizes[1] / 5;

    float* fw = (float*)d_ws;               // N*10 floats
    float* gw = fw + (size_t)N * 10;        // 10*M floats
    float* out = (float*)d_out;

    int total = N + M;
    kent_precompute<<<(total + 255) / 256, 256, 0, stream>>>(pred, targ, fw, gw, N, M);

    dim3 grid((M + 1023) / 1024, (N + 7) / 8);
    kent_kld_main<<<grid, 256, 0, stream>>>(fw, gw, out, N, M);
}